// Round 8
// baseline (2228.796 us; speedup 1.0000x reference)
//
#include <hip/hip_runtime.h>

#define BB 128
#define TT 19
#define MAXCAP 20
#define EMBD 512
#define HIDD 1024
#define NVOCAB 10000
#define KIMG 100352
#define NGATE 4096

#define FC_NT 79                // ceil(10000/128)
#define FC_BLOCKS (FC_NT*2)     // 158: 2 m-tiles(64) x 79 n-tiles(128)
#define LSTM_BLOCKS 128         // 32 j-tiles x 4 m-tiles
#define COMBO_BLOCKS (FC_BLOCKS + LSTM_BLOCKS)   // 286

typedef unsigned short u16;
typedef unsigned int   u32;
using bfrag = __attribute__((ext_vector_type(8))) short;   // 8 bf16 (4 VGPR)
using ff4   = __attribute__((ext_vector_type(4))) float;   // 4 f32 acc
static_assert(sizeof(bfrag) == 16, "bfrag must be 16B");
static_assert(sizeof(ff4) == 16, "ff4 must be 16B");

// split fp32 -> bf16 hi (truncate) + bf16 lo (exact residual, truncated)
__device__ __forceinline__ void bsplit(float x, u16 &h, u16 &l) {
    u32 u = __float_as_uint(x);
    h = (u16)(u >> 16);
    float hf = __uint_as_float(u & 0xffff0000u);
    l = (u16)(__float_as_uint(x - hf) >> 16);
}

// ---------------- zero out predictions (used alone if ws too small) -----------------
// (memset via kernel keeps the launch sequence identical every call)

// ---------------- prep: stable desc sort by length, gather caps, nAct, tail ---------
__global__ void prep_kernel(const int* __restrict__ cap_len,
                            const int* __restrict__ caps,
                            int* __restrict__ sort_ind,
                            int* __restrict__ dec_len,
                            int* __restrict__ nAct,
                            int* __restrict__ caps_s,
                            float* __restrict__ out_tail)
{
    __shared__ int lens[BB];
    __shared__ int sind[BB];
    __shared__ int sdl[BB];
    int i = threadIdx.x;                 // 0..127
    lens[i] = cap_len[i];
    __syncthreads();
    int li = lens[i];
    int r = 0;
    for (int j = 0; j < BB; ++j) {
        int lj = lens[j];
        r += (lj > li) | ((lj == li) & (j < i));   // stable descending rank
    }
    sind[r] = i;
    __syncthreads();
    int src = sind[i];
    sort_ind[i] = src;
    int dl = lens[src] - 1;
    dec_len[i] = dl;
    sdl[i] = dl;
    for (int tt2 = 0; tt2 < MAXCAP; ++tt2) {
        int v = caps[src*MAXCAP + tt2];
        caps_s[i*MAXCAP + tt2] = v;
        out_tail[i*MAXCAP + tt2] = (float)v;       // caps output (as float)
    }
    out_tail[BB*MAXCAP + i] = (float)dl;           // dec_len output
    out_tail[BB*MAXCAP + BB + i] = (float)src;     // sort_ind output
    __syncthreads();
    if (i < 20) {                                  // nAct[t] = #{m : dec_len[m] >= t}
        int cnt = 0;
        for (int j = 0; j < BB; ++j) cnt += (sdl[j] >= i);
        nAct[i] = cnt;
    }
}

// ---------------- init: x_img = img_b (broadcast), h2 = c2 = 0 ----------------------
__global__ void init_kernel(float* __restrict__ x_img,
                            const float* __restrict__ img_b,
                            float* __restrict__ h2,
                            float* __restrict__ c2)
{
    int idx = blockIdx.x*blockDim.x + threadIdx.x;
    int stride = gridDim.x*blockDim.x;
    for (int i = idx; i < BB*EMBD; i += stride) x_img[i] = img_b[i & (EMBD-1)];
    for (int i = idx; i < 2*BB*HIDD; i += stride) { h2[i] = 0.f; c2[i] = 0.f; }
}

// ---------------- fcW pre-split: fp32 -> bf16 hi/lo global arrays (once/launch) -----
__global__ __launch_bounds__(256) void fcw_conv(const float* __restrict__ fcW,
                                                u16* __restrict__ hi,
                                                u16* __restrict__ lo)
{
    size_t i = ((size_t)blockIdx.x*256 + threadIdx.x)*8;   // grid covers exactly
    float4 f0 = *(const float4*)(fcW + i);
    float4 f1 = *(const float4*)(fcW + i + 4);
    float v[8] = {f0.x,f0.y,f0.z,f0.w,f1.x,f1.y,f1.z,f1.w};
    u32 hp[4], lp[4];
    #pragma unroll
    for (int j = 0; j < 4; ++j) {
        u16 h0,l0,h1,l1;
        bsplit(v[2*j],   h0, l0);
        bsplit(v[2*j+1], h1, l1);
        hp[j] = (u32)h0 | ((u32)h1 << 16);
        lp[j] = (u32)l0 | ((u32)l1 << 16);
    }
    *(uint4*)(hi + i) = make_uint4(hp[0],hp[1],hp[2],hp[3]);
    *(uint4*)(lo + i) = make_uint4(lp[0],lp[1],lp[2],lp[3]);
}

// ---------------- x_img split-K GEMM: enc_sorted(128xK) @ img_W(512xK)^T ------------
__global__ __launch_bounds__(256) void img_gemm(const float* __restrict__ enc,
                                                const float* __restrict__ img_W,
                                                const int* __restrict__ sort_ind,
                                                float* __restrict__ x_img)
{
    __shared__ float As[32][68];
    __shared__ float Bs[32][132];
    __shared__ int rows[64];
    const int nt = blockIdx.x;          // 0..3
    const int mt = blockIdx.y & 1;      // 0..1
    const int ks = blockIdx.y >> 1;     // 0..31
    const int m0 = mt*64, n0 = nt*128;
    const int k0 = ks * (KIMG/32);      // 3136 per split, 98 BK-iters
    const int tid = threadIdx.x;
    if (tid < 64) rows[tid] = sort_ind[m0 + tid];
    __syncthreads();
    const int kq = tid & 7;
    const int rr = tid >> 3;
    const int tx = tid & 15, ty = tid >> 4;
    float acc[4][8] = {{0.f}};
    const float* a0p = enc   + (size_t)rows[rr]      * KIMG + k0 + kq*4;
    const float* a1p = enc   + (size_t)rows[rr+32]   * KIMG + k0 + kq*4;
    const float* b0p = img_W + (size_t)(n0+rr)       * KIMG + k0 + kq*4;
    const float* b1p = img_W + (size_t)(n0+rr+32)    * KIMG + k0 + kq*4;
    const float* b2p = img_W + (size_t)(n0+rr+64)    * KIMG + k0 + kq*4;
    const float* b3p = img_W + (size_t)(n0+rr+96)    * KIMG + k0 + kq*4;
    for (int kb = 0; kb < 98; ++kb) {
        float4 a0 = *(const float4*)(a0p + kb*32);
        float4 a1 = *(const float4*)(a1p + kb*32);
        float4 b0 = *(const float4*)(b0p + kb*32);
        float4 b1 = *(const float4*)(b1p + kb*32);
        float4 b2 = *(const float4*)(b2p + kb*32);
        float4 b3 = *(const float4*)(b3p + kb*32);
        __syncthreads();
        As[kq*4+0][rr]    = a0.x; As[kq*4+1][rr]    = a0.y; As[kq*4+2][rr]    = a0.z; As[kq*4+3][rr]    = a0.w;
        As[kq*4+0][rr+32] = a1.x; As[kq*4+1][rr+32] = a1.y; As[kq*4+2][rr+32] = a1.z; As[kq*4+3][rr+32] = a1.w;
        Bs[kq*4+0][rr]    = b0.x; Bs[kq*4+1][rr]    = b0.y; Bs[kq*4+2][rr]    = b0.z; Bs[kq*4+3][rr]    = b0.w;
        Bs[kq*4+0][rr+32] = b1.x; Bs[kq*4+1][rr+32] = b1.y; Bs[kq*4+2][rr+32] = b1.z; Bs[kq*4+3][rr+32] = b1.w;
        Bs[kq*4+0][rr+64] = b2.x; Bs[kq*4+1][rr+64] = b2.y; Bs[kq*4+2][rr+64] = b2.z; Bs[kq*4+3][rr+64] = b2.w;
        Bs[kq*4+0][rr+96] = b3.x; Bs[kq*4+1][rr+96] = b3.y; Bs[kq*4+2][rr+96] = b3.z; Bs[kq*4+3][rr+96] = b3.w;
        __syncthreads();
        #pragma unroll
        for (int kk = 0; kk < 32; ++kk) {
            float4 av  = *(const float4*)&As[kk][ty*4];
            float4 blo = *(const float4*)&Bs[kk][tx*4];
            float4 bhi = *(const float4*)&Bs[kk][64 + tx*4];
            float aa[4] = {av.x,av.y,av.z,av.w};
            float bb[8] = {blo.x,blo.y,blo.z,blo.w,bhi.x,bhi.y,bhi.z,bhi.w};
            #pragma unroll
            for (int i2 = 0; i2 < 4; ++i2)
                #pragma unroll
                for (int j2 = 0; j2 < 8; ++j2)
                    acc[i2][j2] = fmaf(aa[i2], bb[j2], acc[i2][j2]);
        }
    }
    #pragma unroll
    for (int i2 = 0; i2 < 4; ++i2) {
        int m = m0 + ty*4 + i2;
        #pragma unroll
        for (int j2 = 0; j2 < 4; ++j2)
            atomicAdd(&x_img[m*EMBD + n0 + tx*4 + j2],      acc[i2][j2]);
        #pragma unroll
        for (int j2 = 0; j2 < 4; ++j2)
            atomicAdd(&x_img[m*EMBD + n0 + 64 + tx*4 + j2], acc[i2][4+j2]);
    }
}

// ---------------- xg: xg[t] = x_t @ W_ih^T + b_ih + b_hh ----------------------------
__global__ __launch_bounds__(256) void xg_gemm(int tBase,
    const float* __restrict__ x_img, const float* __restrict__ emb_W,
    const int* __restrict__ caps_s,
    const float* __restrict__ W_ih,
    const float* __restrict__ b_ih, const float* __restrict__ b_hh,
    float* __restrict__ xgOut)
{
    __shared__ float As[32][132];
    __shared__ float Bs[32][68];
    __shared__ const float* Arow[128];
    const int t  = tBase + blockIdx.y;
    const int n0 = blockIdx.x * 64;
    const int tid = threadIdx.x;
    if (tid < 128) {
        Arow[tid] = (t == 0) ? (x_img + tid*EMBD)
                             : (emb_W + (size_t)caps_s[tid*MAXCAP + (t-1)]*EMBD);
    }
    __syncthreads();
    const int kq = tid & 7, rr = tid >> 3;
    const int tx = tid & 15, ty = tid >> 4;
    float acc[8][4] = {{0.f}};
    for (int kb = 0; kb < 16; ++kb) {   // K = 512
        const int k = kb*32 + kq*4;
        float4 a[4];
        #pragma unroll
        for (int rd = 0; rd < 4; ++rd)
            a[rd] = *(const float4*)(Arow[rd*32 + rr] + k);
        float4 b0 = *(const float4*)&W_ih[(size_t)(n0+rr)   *EMBD + k];
        float4 b1 = *(const float4*)&W_ih[(size_t)(n0+rr+32)*EMBD + k];
        __syncthreads();
        #pragma unroll
        for (int rd = 0; rd < 4; ++rd) {
            As[kq*4+0][rd*32+rr] = a[rd].x; As[kq*4+1][rd*32+rr] = a[rd].y;
            As[kq*4+2][rd*32+rr] = a[rd].z; As[kq*4+3][rd*32+rr] = a[rd].w;
        }
        Bs[kq*4+0][rr]    = b0.x; Bs[kq*4+1][rr]    = b0.y; Bs[kq*4+2][rr]    = b0.z; Bs[kq*4+3][rr]    = b0.w;
        Bs[kq*4+0][rr+32] = b1.x; Bs[kq*4+1][rr+32] = b1.y; Bs[kq*4+2][rr+32] = b1.z; Bs[kq*4+3][rr+32] = b1.w;
        __syncthreads();
        #pragma unroll
        for (int kk = 0; kk < 32; ++kk) {
            float4 alo = *(const float4*)&As[kk][ty*4];
            float4 ahi = *(const float4*)&As[kk][64 + ty*4];
            float4 bv  = *(const float4*)&Bs[kk][tx*4];
            float aa[8] = {alo.x,alo.y,alo.z,alo.w,ahi.x,ahi.y,ahi.z,ahi.w};
            float bb[4] = {bv.x,bv.y,bv.z,bv.w};
            #pragma unroll
            for (int i2 = 0; i2 < 8; ++i2)
                #pragma unroll
                for (int j2 = 0; j2 < 4; ++j2)
                    acc[i2][j2] = fmaf(aa[i2], bb[j2], acc[i2][j2]);
        }
    }
    #pragma unroll
    for (int i2 = 0; i2 < 8; ++i2) {
        int m = (i2 < 4) ? (ty*4 + i2) : (64 + ty*4 + (i2-4));
        #pragma unroll
        for (int j2 = 0; j2 < 4; ++j2) {
            int n = n0 + tx*4 + j2;
            xgOut[((size_t)blockIdx.y*BB + m)*NGATE + n] = acc[i2][j2] + b_ih[n] + b_hh[n];
        }
    }
}

// ---------------- combo: blocks [0,158) = fc (MFMA) step t-1; rest lstm step t ------
// fc: 64m x 128n per block; 4 waves x (16m x 8 nt); split-bf16, 3 mfma products.
// lstm: fp32, 32m x 32j x 4 sections; writes h/c + bf16 hi/lo shadows of h.
__global__ __launch_bounds__(256) void combo_kernel(int t,
    float* __restrict__ h2, float* __restrict__ c2,
    const float* __restrict__ W_hh,
    const float* __restrict__ xgt,
    const float* __restrict__ fc_W, const float* __restrict__ fc_b,
    const int* __restrict__ nAct,
    float* __restrict__ out,
    u16* __restrict__ h_hi2, u16* __restrict__ h_lo2,
    const u16* __restrict__ fcw_hi, const u16* __restrict__ fcw_lo,
    int preconv)
{
    __shared__ __align__(16) float smem[32*68 + 32*132];   // 25.6 KB
    const int tid = threadIdx.x;
    const int bid = blockIdx.x;

    if (bid < FC_BLOCKS) {
        // ---------- fc path (MFMA): preds[t-1] = h @ fc_W^T + fc_b ------------------
        if (t == 0) return;
        const int nA = nAct[t-1];
        const int nt0 = bid % FC_NT, mt = bid / FC_NT;
        const int m0 = mt*64, n0 = nt0*128;
        if (m0 >= nA) return;
        u16* H = (u16*)smem;            // [128][40] bf16-hi, k=0..31 used
        u16* L = H + 128*40;            // [128][40] bf16-lo
        const int lane = tid & 63, w = tid >> 6;
        const int lr = lane & 15, lk = lane >> 4;
        const u16* pAh = h_hi2 + (size_t)(t & 1)*BB*HIDD + (size_t)(m0 + w*16 + lr)*HIDD;
        const u16* pAl = h_lo2 + (size_t)(t & 1)*BB*HIDD + (size_t)(m0 + w*16 + lr)*HIDD;
        const int row = tid >> 1, half = tid & 1;          // staging role
        const int gn = n0 + row;
        const bool gv = gn < NVOCAB;
        ff4 acc[8];
        #pragma unroll
        for (int i = 0; i < 8; ++i) acc[i] = (ff4){0.f,0.f,0.f,0.f};

        for (int ks = 0; ks < 32; ++ks) {                  // K = 1024
            const int k0 = ks*32;
            __syncthreads();                               // LDS safe to overwrite
            const int dst = row*40 + half*16;
            if (preconv) {
                uint4 z = make_uint4(0,0,0,0);
                const uint4* ph = (const uint4*)(fcw_hi + (size_t)gn*HIDD + k0 + half*16);
                const uint4* pl = (const uint4*)(fcw_lo + (size_t)gn*HIDD + k0 + half*16);
                uint4 h0 = gv ? ph[0] : z, h1 = gv ? ph[1] : z;
                uint4 l0 = gv ? pl[0] : z, l1 = gv ? pl[1] : z;
                *(uint4*)&H[dst]   = h0;  *(uint4*)&H[dst+8] = h1;
                *(uint4*)&L[dst]   = l0;  *(uint4*)&L[dst+8] = l1;
            } else {
                float v[16];
                const float4* pf = (const float4*)(fc_W + (size_t)gn*HIDD + k0 + half*16);
                #pragma unroll
                for (int q = 0; q < 4; ++q) {
                    float4 f = gv ? pf[q] : make_float4(0.f,0.f,0.f,0.f);
                    v[q*4+0]=f.x; v[q*4+1]=f.y; v[q*4+2]=f.z; v[q*4+3]=f.w;
                }
                u32 hp[8], lp[8];
                #pragma unroll
                for (int q = 0; q < 8; ++q) {
                    u16 h0,l0,h1,l1;
                    bsplit(v[2*q],h0,l0); bsplit(v[2*q+1],h1,l1);
                    hp[q] = (u32)h0 | ((u32)h1<<16);
                    lp[q] = (u32)l0 | ((u32)l1<<16);
                }
                *(uint4*)&H[dst]   = make_uint4(hp[0],hp[1],hp[2],hp[3]);
                *(uint4*)&H[dst+8] = make_uint4(hp[4],hp[5],hp[6],hp[7]);
                *(uint4*)&L[dst]   = make_uint4(lp[0],lp[1],lp[2],lp[3]);
                *(uint4*)&L[dst+8] = make_uint4(lp[4],lp[5],lp[6],lp[7]);
            }
            __syncthreads();
            bfrag a_h = *(const bfrag*)(pAh + k0 + lk*8);
            bfrag a_l = *(const bfrag*)(pAl + k0 + lk*8);
            #pragma unroll
            for (int nt = 0; nt < 8; ++nt) {
                const int br = (nt*16 + lr)*40 + lk*8;
                bfrag b_h = *(const bfrag*)&H[br];
                bfrag b_l = *(const bfrag*)&L[br];
                acc[nt] = __builtin_amdgcn_mfma_f32_16x16x32_bf16(a_h, b_h, acc[nt], 0,0,0);
                acc[nt] = __builtin_amdgcn_mfma_f32_16x16x32_bf16(a_h, b_l, acc[nt], 0,0,0);
                acc[nt] = __builtin_amdgcn_mfma_f32_16x16x32_bf16(a_l, b_h, acc[nt], 0,0,0);
            }
        }
        // epilogue: D col=lane&15, row=(lane>>4)*4+reg  [HW-verified]
        #pragma unroll
        for (int nt = 0; nt < 8; ++nt) {
            const int n = n0 + nt*16 + lr;
            if (n >= NVOCAB) continue;
            const float bias = fc_b[n];
            #pragma unroll
            for (int r = 0; r < 4; ++r) {
                const int m = m0 + w*16 + lk*4 + r;
                if (m < nA)
                    out[(size_t)m*(TT*NVOCAB) + (size_t)(t-1)*NVOCAB + n] = acc[nt][r] + bias;
            }
        }
    } else {
        // ---------- lstm path: gates(h-part) + cell for step t ----------------------
        if (t > TT-1) return;
        const int nA = nAct[t];
        const int lb = bid - FC_BLOCKS;
        const int jt = lb & 31, mt2 = lb >> 5;
        const int j0 = jt*32, m0 = mt2*32;
        if (m0 >= nA) return;
        float (*As)[36]   = (float (*)[36])smem;
        float (*BsL)[132] = (float (*)[132])(smem + 32*36);
        const float* hr  = h2 + (size_t)(t & 1)*BB*HIDD;
        float*       hw  = h2 + (size_t)((t+1) & 1)*BB*HIDD;
        const float* cr  = c2 + (size_t)(t & 1)*BB*HIDD;
        float*       cw  = c2 + (size_t)((t+1) & 1)*BB*HIDD;
        u16* hwh = h_hi2 + (size_t)((t+1) & 1)*BB*HIDD;
        u16* hwl = h_lo2 + (size_t)((t+1) & 1)*BB*HIDD;
        const int kq = tid & 7, rr = tid >> 3;
        const int tx = tid & 31, ty = tid >> 5;
        float acc[4][4] = {{0.f}};
        for (int kb = 0; kb < 32; ++kb) {             // K = 1024
            const int k = kb*32 + kq*4;
            float4 a = *(const float4*)&hr[(size_t)(m0+rr)*HIDD + k];
            float4 b[4];
            #pragma unroll
            for (int s = 0; s < 4; ++s)
                b[s] = *(const float4*)&W_hh[(size_t)(s*HIDD + j0 + rr)*HIDD + k];
            __syncthreads();
            As[kq*4+0][rr] = a.x; As[kq*4+1][rr] = a.y; As[kq*4+2][rr] = a.z; As[kq*4+3][rr] = a.w;
            #pragma unroll
            for (int s = 0; s < 4; ++s) {
                BsL[kq*4+0][s*33+rr] = b[s].x; BsL[kq*4+1][s*33+rr] = b[s].y;
                BsL[kq*4+2][s*33+rr] = b[s].z; BsL[kq*4+3][s*33+rr] = b[s].w;
            }
            __syncthreads();
            #pragma unroll
            for (int kk = 0; kk < 32; ++kk) {
                float4 av = *(const float4*)&As[kk][ty*4];
                float aa[4] = {av.x, av.y, av.z, av.w};
                float bb[4] = {BsL[kk][0*33+tx], BsL[kk][1*33+tx],
                               BsL[kk][2*33+tx], BsL[kk][3*33+tx]};
                #pragma unroll
                for (int s = 0; s < 4; ++s)
                    #pragma unroll
                    for (int r2 = 0; r2 < 4; ++r2)
                        acc[s][r2] = fmaf(aa[r2], bb[s], acc[s][r2]);
            }
        }
        const int j = j0 + tx;
        #pragma unroll
        for (int r2 = 0; r2 < 4; ++r2) {
            const int m = m0 + ty*4 + r2;
            if (m >= nA) continue;
            const float iv = acc[0][r2] + xgt[(size_t)m*NGATE + j];
            const float fv = acc[1][r2] + xgt[(size_t)m*NGATE + HIDD + j];
            const float gv = acc[2][r2] + xgt[(size_t)m*NGATE + 2*HIDD + j];
            const float ov = acc[3][r2] + xgt[(size_t)m*NGATE + 3*HIDD + j];
            const float ig = 1.f/(1.f + expf(-iv));
            const float fg = 1.f/(1.f + expf(-fv));
            const float gg = tanhf(gv);
            const float og = 1.f/(1.f + expf(-ov));
            const float cn = fg*cr[(size_t)m*HIDD + j] + ig*gg;
            const float hn = og*tanhf(cn);
            cw[(size_t)m*HIDD + j] = cn;
            hw[(size_t)m*HIDD + j] = hn;
            u16 sh, sl; bsplit(hn, sh, sl);
            hwh[(size_t)m*HIDD + j] = sh;
            hwl[(size_t)m*HIDD + j] = sl;
        }
    }
}

extern "C" void kernel_launch(void* const* d_in, const int* in_sizes, int n_in,
                              void* d_out, int out_size, void* d_ws, size_t ws_size,
                              hipStream_t stream)
{
    const float* enc   = (const float*)d_in[0];
    const int*   caps  = (const int*)d_in[1];
    const int*   clen  = (const int*)d_in[2];
    const float* emb_W = (const float*)d_in[3];
    const float* img_W = (const float*)d_in[4];
    const float* img_b = (const float*)d_in[5];
    const float* W_ih  = (const float*)d_in[6];
    const float* W_hh  = (const float*)d_in[7];
    const float* b_ih  = (const float*)d_in[8];
    const float* b_hh  = (const float*)d_in[9];
    const float* fc_W  = (const float*)d_in[10];
    const float* fc_b  = (const float*)d_in[11];
    float* out = (float*)d_out;

    // workspace layout (float-unit arithmetic; u16 regions counted in float slots)
    int* sort_ind = (int*)d_ws;                      // 128
    int* dec_len  = sort_ind + BB;                   // 128
    int* nAct     = dec_len + BB;                    // 20 (+pad)
    int* caps_s   = nAct + 24;                       // 128*20
    float* x_img  = (float*)(caps_s + BB*MAXCAP);    // 128*512
    float* h2     = x_img + BB*EMBD;                 // 2*128*1024 (ping-pong)
    float* c2     = h2 + 2*BB*HIDD;                  // 2*128*1024
    u16*   h_hi2  = (u16*)(c2 + 2*BB*HIDD);          // 2*128*1024 u16
    u16*   h_lo2  = h_hi2 + 2*BB*HIDD;               // 2*128*1024 u16
    float* xg     = (float*)(h_lo2 + 2*BB*HIDD);     // TT*128*4096 (full) or 1 step
    u16*   fcw_hi = (u16*)(xg + (size_t)TT*BB*NGATE);// 10000*1024 u16
    u16*   fcw_lo = fcw_hi + (size_t)NVOCAB*HIDD;    // 10000*1024 u16

    const size_t min_end = (size_t)((char*)(xg + (size_t)BB*NGATE) - (char*)d_ws);
    const size_t xg_end  = (size_t)((char*)fcw_hi - (char*)d_ws);
    const size_t all_end = (size_t)((char*)(fcw_lo + (size_t)NVOCAB*HIDD) - (char*)d_ws);
    const bool ws_ok   = ws_size >= min_end;   // ~6.6 MB: hard floor, else no-op (avoid OOB fault)
    const bool full    = ws_size >= xg_end;    // ~44 MB: 19-step xg precompute
    const bool preconv = ws_size >= all_end;   // ~84 MB: + pre-split fcW bf16 hi/lo

    hipMemsetAsync(out, 0, (size_t)BB*TT*NVOCAB*sizeof(float), stream);
    if (!ws_ok) return;   // workspace too small: clean (wrong-answer) exit, not a fault

    float* out_tail = out + (size_t)BB*TT*NVOCAB;

    hipLaunchKernelGGL(prep_kernel, dim3(1), dim3(BB), 0, stream,
                       clen, caps, sort_ind, dec_len, nAct, caps_s, out_tail);
    hipLaunchKernelGGL(init_kernel, dim3(512), dim3(256), 0, stream,
                       x_img, img_b, h2, c2);
    if (preconv) {   // 10000*1024/8/256 = 5000 blocks, exact
        hipLaunchKernelGGL(fcw_conv, dim3(5000), dim3(256), 0, stream,
                           fc_W, fcw_hi, fcw_lo);
    }
    hipLaunchKernelGGL(img_gemm, dim3(4, 64), dim3(256), 0, stream,
                       enc, img_W, sort_ind, x_img);
    if (full) {
        hipLaunchKernelGGL(xg_gemm, dim3(64, TT), dim3(256), 0, stream,
                           0, x_img, emb_W, caps_s, W_ih, b_ih, b_hh, xg);
    }
    for (int t = 0; t <= TT; ++t) {
        if (!full && t < TT) {
            hipLaunchKernelGGL(xg_gemm, dim3(64, 1), dim3(256), 0, stream,
                               t, x_img, emb_W, caps_s, W_ih, b_ih, b_hh, xg);
        }
        const float* xgt = full ? (xg + (size_t)(t < TT ? t : 0)*BB*NGATE) : xg;
        hipLaunchKernelGGL(combo_kernel, dim3(COMBO_BLOCKS), dim3(256), 0, stream,
                           t, h2, c2, W_hh, xgt, fc_W, fc_b, nAct, out,
                           h_hi2, h_lo2, fcw_hi, fcw_lo, (int)preconv);
    }
}